// Round 1
// baseline (755.962 us; speedup 1.0000x reference)
//
#include <hip/hip_runtime.h>
#include <cstdint>

// Problem constants
static constexpr int B_ = 8, C_ = 512, L_ = 4096, NG_ = 32;
static constexpr float RSCALE = 0.04419417382415922f; // 1/sqrt(512)

using f32x4  = __attribute__((ext_vector_type(4))) float;
using bf16x8 = __attribute__((ext_vector_type(8))) short;

__device__ __forceinline__ uint16_t f2bf(float f) {
  union { float f; uint32_t u; } v{f};
  uint32_t r = (v.u + 0x7fffu + ((v.u >> 16) & 1u)) >> 16;
  return (uint16_t)r;
}

// ---------------- K0: f32 -> bf16 convert (weights) ----------------
__global__ __launch_bounds__(256) void k_cvt_bf16(const float* __restrict__ in,
                                                  uint16_t* __restrict__ out, int n) {
  int i = (blockIdx.x * 256 + threadIdx.x) * 4;
  if (i + 3 < n) {
    float4 v = *(const float4*)(in + i);
    union { uint16_t s[4]; uint2 u; } o;
    o.s[0] = f2bf(v.x); o.s[1] = f2bf(v.y); o.s[2] = f2bf(v.z); o.s[3] = f2bf(v.w);
    *(uint2*)(out + i) = o.u;
  }
}

// ---------------- K1: GroupNorm stats ----------------
// one block per (b,g); group data is contiguous: 16 ch * 4096 = 65536 floats
__global__ __launch_bounds__(256) void k_gnstats(const float* __restrict__ x,
                                                 float* __restrict__ mu, float* __restrict__ rs) {
  int bg = blockIdx.x;
  const float* p = x + (size_t)bg * (16 * L_);
  float s = 0.f, s2 = 0.f;
#pragma unroll 8
  for (int i = 0; i < 64; ++i) {
    float4 v = *(const float4*)(p + (threadIdx.x + i * 256) * 4);
    s  += v.x + v.y + v.z + v.w;
    s2 += v.x * v.x + v.y * v.y + v.z * v.z + v.w * v.w;
  }
  for (int o = 32; o; o >>= 1) { s += __shfl_down(s, o); s2 += __shfl_down(s2, o); }
  __shared__ float as_[4], as2_[4];
  int w = threadIdx.x >> 6;
  if ((threadIdx.x & 63) == 0) { as_[w] = s; as2_[w] = s2; }
  __syncthreads();
  if (threadIdx.x == 0) {
    float S = as_[0] + as_[1] + as_[2] + as_[3];
    float S2 = as2_[0] + as2_[1] + as2_[2] + as2_[3];
    float m = S / 65536.0f;
    float var = S2 / 65536.0f - m * m;
    mu[bg] = m; rs[bg] = rsqrtf(var + 1e-5f);
  }
}

// ---------------- K2: normalize + transpose: x[b][c][l] f32 -> xnT[b][l][c] bf16 ----------------
__global__ __launch_bounds__(256) void k_normT(const float* __restrict__ x,
                                               const float* __restrict__ nw, const float* __restrict__ nb,
                                               const float* __restrict__ mu, const float* __restrict__ rs,
                                               uint16_t* __restrict__ xnT) {
  __shared__ __align__(16) uint16_t t[64][72]; // [l][c], padded row 144B
  int l0 = blockIdx.x * 64, c0 = blockIdx.y * 64, b = blockIdx.z;
#pragma unroll
  for (int i = 0; i < 4; ++i) {
    int idx = threadIdx.x + i * 256;        // 0..1023
    int row = idx >> 4, q = idx & 15;       // row = c-local, q = which float4 along l
    int c = c0 + row;
    float m_ = mu[b * NG_ + (c >> 4)], r_ = rs[b * NG_ + (c >> 4)];
    float sc = r_ * nw[c], sh = nb[c] - m_ * sc;
    float4 v = *(const float4*)(x + (size_t)(b * C_ + c) * L_ + l0 + q * 4);
    int lb = q * 4;
    t[lb + 0][row] = f2bf(v.x * sc + sh);
    t[lb + 1][row] = f2bf(v.y * sc + sh);
    t[lb + 2][row] = f2bf(v.z * sc + sh);
    t[lb + 3][row] = f2bf(v.w * sc + sh);
  }
  __syncthreads();
#pragma unroll
  for (int i = 0; i < 2; ++i) {
    int idx = threadIdx.x + i * 256;        // 0..511
    int row = idx >> 3, ch = idx & 7;       // row = l-local
    uint4 v = *(const uint4*)(&t[row][ch * 8]);
    *(uint4*)(xnT + (size_t)(b * L_ + l0 + row) * C_ + c0 + ch * 8) = v;
  }
}

// ---------------- K4: V transpose: qkvT[b][l][1024+c] -> vn[b][c][l] ----------------
__global__ __launch_bounds__(256) void k_vT(const uint16_t* __restrict__ qkvT, uint16_t* __restrict__ vn) {
  __shared__ __align__(16) uint16_t t[64][72]; // [c][l]
  int l0 = blockIdx.x * 64, c0 = blockIdx.y * 64, b = blockIdx.z;
#pragma unroll
  for (int i = 0; i < 2; ++i) {
    int idx = threadIdx.x + i * 256;
    int row = idx >> 3, ch = idx & 7;       // row = l-local
    uint16_t v[8];
    *(uint4*)v = *(const uint4*)(qkvT + (size_t)(b * L_ + l0 + row) * 1536 + 1024 + c0 + ch * 8);
#pragma unroll
    for (int j = 0; j < 8; ++j) t[ch * 8 + j][row] = v[j];
  }
  __syncthreads();
#pragma unroll
  for (int i = 0; i < 2; ++i) {
    int idx = threadIdx.x + i * 256;
    int row = idx >> 3, ch = idx & 7;       // row = c-local
    *(uint4*)(vn + (size_t)(b * C_ + c0 + row) * L_ + l0 + ch * 8) = *(const uint4*)(&t[row][ch * 8]);
  }
}

// ---------------- GEMM (128x128 tile, BK=64, 4 waves, swizzled LDS) ----------------
// MODE 0: qkvT[b][l][o] = xnT[b] @ Wq^T ; epilogue: +qkv_b[o], *RSCALE for o<512, bf16 store (ldc=1536)
// MODE 1: out[b][oc][l] = Wo @ Ot[b]^T  ; epilogue: +out_b[oc] + x residual, f32 store (ldc=4096)
template <int MODE>
__global__ __launch_bounds__(256, 2) void k_gemm(const uint16_t* __restrict__ Ag, int lda, long long strideA,
                                                 const uint16_t* __restrict__ Bg, int ldb, long long strideB,
                                                 void* __restrict__ Cg, long long strideC,
                                                 const float* __restrict__ bias,
                                                 const float* __restrict__ resid) {
  __shared__ __align__(16) uint16_t Asm[128 * 64], Bsm[128 * 64];
  int b = blockIdx.z;
  int m0 = blockIdx.y * 128, n0 = blockIdx.x * 128;
  const uint16_t* A = Ag + (size_t)b * strideA;
  const uint16_t* Bp = Bg + (size_t)b * strideB;
  int lane = threadIdx.x & 63, w = threadIdx.x >> 6;
  int wm = w >> 1, wn = w & 1;
  int l15 = lane & 15, lhi = lane >> 4;
  f32x4 acc[4][4] = {};
  for (int kt = 0; kt < 512; kt += 64) {
#pragma unroll
    for (int i = 0; i < 4; ++i) {
      int idx = threadIdx.x + i * 256;
      int row = idx >> 3, cs = idx & 7, cg = cs ^ (row & 7);
      *(uint4*)(Asm + row * 64 + cs * 8) = *(const uint4*)(A + (size_t)(m0 + row) * lda + kt + cg * 8);
      *(uint4*)(Bsm + row * 64 + cs * 8) = *(const uint4*)(Bp + (size_t)(n0 + row) * ldb + kt + cg * 8);
    }
    __syncthreads();
#pragma unroll
    for (int kk = 0; kk < 2; ++kk) {
      bf16x8 af[4], bfr[4];
      int chunk = kk * 4 + lhi;
#pragma unroll
      for (int m = 0; m < 4; ++m) {
        int row = wm * 64 + m * 16 + l15;
        af[m] = *(const bf16x8*)(Asm + row * 64 + ((chunk ^ (row & 7)) << 3));
      }
#pragma unroll
      for (int n = 0; n < 4; ++n) {
        int row = wn * 64 + n * 16 + l15;
        bfr[n] = *(const bf16x8*)(Bsm + row * 64 + ((chunk ^ (row & 7)) << 3));
      }
#pragma unroll
      for (int m = 0; m < 4; ++m)
#pragma unroll
        for (int n = 0; n < 4; ++n)
          acc[m][n] = __builtin_amdgcn_mfma_f32_16x16x32_bf16(af[m], bfr[n], acc[m][n], 0, 0, 0);
    }
    __syncthreads();
  }
  if (MODE == 0) {
    uint16_t* Cp = (uint16_t*)Cg + (size_t)b * strideC;
#pragma unroll
    for (int n = 0; n < 4; ++n) {
      int col = n0 + wn * 64 + n * 16 + l15;
      float bs = bias[col];
      float scl = (col < 512) ? RSCALE : 1.0f;
#pragma unroll
      for (int m = 0; m < 4; ++m) {
        int rowb = m0 + wm * 64 + m * 16 + lhi * 4;
#pragma unroll
        for (int r = 0; r < 4; ++r)
          Cp[(size_t)(rowb + r) * 1536 + col] = f2bf((acc[m][n][r] + bs) * scl);
      }
    }
  } else {
    float* Cp = (float*)Cg + (size_t)b * strideC;
    const float* Xp = resid + (size_t)b * strideC;
#pragma unroll
    for (int m = 0; m < 4; ++m) {
      int rowb = m0 + wm * 64 + m * 16 + lhi * 4;
#pragma unroll
      for (int n = 0; n < 4; ++n) {
        int col = n0 + wn * 64 + n * 16 + l15;
#pragma unroll
        for (int r = 0; r < 4; ++r) {
          float v = acc[m][n][r] + bias[rowb + r] + Xp[(size_t)(rowb + r) * 4096 + col];
          Cp[(size_t)(rowb + r) * 4096 + col] = v;
        }
      }
    }
  }
}

// ---------------- K5: flash attention ----------------
// S^T[s][l] = sum_c Kt[s][c] * Qt_scaled[l][c]; online softmax over s; Ot[l][c] = sum_s P[l][s] V[c][s]
__global__ __launch_bounds__(512, 2) void k_attn(const uint16_t* __restrict__ qkvT,
                                                 const uint16_t* __restrict__ vn,
                                                 uint16_t* __restrict__ ot) {
  __shared__ __align__(16) uint16_t qs[64 * 512];   // Qt tile [l][c]
  __shared__ __align__(16) uint16_t kvs[64 * 512];  // K tile [s][c] then V tile [c][s]
  __shared__ __align__(16) uint16_t ps[64 * 64];    // P tile [l][s]
  __shared__ __align__(16) float redm[2][4][16], reds[2][4][16];
  __shared__ __align__(16) float mrun[64], lrun[64], alph[64];

  const int tid = threadIdx.x, lane = tid & 63, w = tid >> 6;
  const int l15 = lane & 15, lhi = lane >> 4;
  const int b = blockIdx.y, q0 = blockIdx.x * 64;
  const int nf = w & 3, mh = w >> 2;

  const uint16_t* qg = qkvT + (size_t)(b * L_ + q0) * 1536;
  const uint16_t* kg = qkvT + (size_t)b * L_ * 1536 + 512;
  const uint16_t* vg = vn + (size_t)b * C_ * L_;

  // stage Q once: 64 rows x 1024B, 16B-chunk xor swizzle
#pragma unroll
  for (int i = 0; i < 8; ++i) {
    int idx = tid + i * 512;
    int row = idx >> 6, cs = idx & 63, cg = cs ^ (row & 7);
    *(uint4*)(qs + row * 512 + cs * 8) = *(const uint4*)(qg + (size_t)row * 1536 + cg * 8);
  }
  if (tid < 64) { mrun[tid] = -1e30f; lrun[tid] = 0.0f; }

  f32x4 acc[4][4] = {};

  for (int st = 0; st < 64; ++st) {
    __syncthreads(); // previous PV finished reading kvs
    {
      uint4 tmp[8];
#pragma unroll
      for (int i = 0; i < 8; ++i) {
        int idx = tid + i * 512;
        int row = idx >> 6, cs = idx & 63, cg = cs ^ (row & 7);
        tmp[i] = *(const uint4*)(kg + (size_t)(st * 64 + row) * 1536 + cg * 8);
      }
#pragma unroll
      for (int i = 0; i < 8; ++i) {
        int idx = tid + i * 512;
        int row = idx >> 6, cs = idx & 63;
        *(uint4*)(kvs + row * 512 + cs * 8) = tmp[i];
      }
    }
    __syncthreads(); // K tile ready (and Q on first iter)

    // S^T = Kt x Q ; wave covers m-frags {2mh, 2mh+1} (s), n-frag nf (l)
    f32x4 sfr[2] = {};
#pragma unroll
    for (int kc = 0; kc < 16; ++kc) {
      int chunk = kc * 4 + lhi;
      int qrow = nf * 16 + l15;
      bf16x8 bq = *(const bf16x8*)(qs + qrow * 512 + ((chunk ^ (qrow & 7)) << 3));
#pragma unroll
      for (int i = 0; i < 2; ++i) {
        int srow = (mh * 2 + i) * 16 + l15;
        bf16x8 ak = *(const bf16x8*)(kvs + srow * 512 + ((chunk ^ (srow & 7)) << 3));
        sfr[i] = __builtin_amdgcn_mfma_f32_16x16x32_bf16(ak, bq, sfr[i], 0, 0, 0);
      }
    }

    // partial column-max over this wave's 32 s-rows
    float pm = -1e30f;
#pragma unroll
    for (int i = 0; i < 2; ++i)
#pragma unroll
      for (int r = 0; r < 4; ++r) pm = fmaxf(pm, sfr[i][r]);
    pm = fmaxf(pm, __shfl_xor(pm, 16));
    pm = fmaxf(pm, __shfl_xor(pm, 32));
    if (lhi == 0) redm[mh][nf][l15] = pm;
    __syncthreads(); // redm ready; all K reads done -> kvs reusable for V

    // issue V global loads early (overlap with softmax math)
    uint4 vtmp[8];
#pragma unroll
    for (int i = 0; i < 8; ++i) {
      int idx = tid + i * 512;
      int row = idx >> 3, cs = idx & 7, cg = cs ^ (row & 7);
      vtmp[i] = *(const uint4*)(vg + (size_t)row * L_ + st * 64 + cg * 8);
    }

    float m_old = mrun[nf * 16 + l15];
    float tm = fmaxf(redm[0][nf][l15], redm[1][nf][l15]);
    float m_new = fmaxf(m_old, tm);
    float p[2][4];
    float psum = 0.f;
#pragma unroll
    for (int i = 0; i < 2; ++i)
#pragma unroll
      for (int r = 0; r < 4; ++r) { p[i][r] = __expf(sfr[i][r] - m_new); psum += p[i][r]; }
    psum += __shfl_xor(psum, 16);
    psum += __shfl_xor(psum, 32);
    if (lhi == 0) reds[mh][nf][l15] = psum;

    // write P (bf16) to ps[l][s]; 4 consecutive s per lane -> 8B write
    {
      int l = nf * 16 + l15;
#pragma unroll
      for (int i = 0; i < 2; ++i) {
        int s0 = (mh * 2 + i) * 16 + lhi * 4;
        union { uint16_t h[4]; uint2 u; } pk;
#pragma unroll
        for (int r = 0; r < 4; ++r) pk.h[r] = f2bf(p[i][r]);
        int chunk = s0 >> 3, off = s0 & 7;
        *(uint2*)(ps + l * 64 + ((chunk ^ (l & 7)) << 3) + off) = pk.u;
      }
    }
    // V LDS writes ([c][s] layout)
#pragma unroll
    for (int i = 0; i < 8; ++i) {
      int idx = tid + i * 512;
      int row = idx >> 3, cs = idx & 7;
      *(uint4*)(kvs + row * 64 + cs * 8) = vtmp[i];
    }
    __syncthreads(); // reds/ps/V ready; all mrun reads done

    if (tid < 64) {
      float mo = mrun[tid];
      float tmax = fmaxf(redm[0][tid >> 4][tid & 15], redm[1][tid >> 4][tid & 15]);
      float mn = fmaxf(mo, tmax);
      float a = __expf(mo - mn);
      float tsum = reds[0][tid >> 4][tid & 15] + reds[1][tid >> 4][tid & 15];
      lrun[tid] = lrun[tid] * a + tsum;
      mrun[tid] = mn;
      alph[tid] = a;
    }
    __syncthreads(); // alph ready

    // O rescale + PV: Ot[l][c] += P[l][s] * V[c][s]; wave owns c in [w*64, w*64+64)
#pragma unroll
    for (int m = 0; m < 4; ++m) {
      f32x4 a4 = *(const f32x4*)(&alph[m * 16 + lhi * 4]);
#pragma unroll
      for (int n = 0; n < 4; ++n)
#pragma unroll
        for (int r = 0; r < 4; ++r) acc[m][n][r] *= a4[r];
    }
#pragma unroll
    for (int kk = 0; kk < 2; ++kk) {
      int chunk = kk * 4 + lhi;
      bf16x8 pa[4], vb[4];
#pragma unroll
      for (int m = 0; m < 4; ++m) {
        int row = m * 16 + l15;
        pa[m] = *(const bf16x8*)(ps + row * 64 + ((chunk ^ (row & 7)) << 3));
      }
#pragma unroll
      for (int n = 0; n < 4; ++n) {
        int row = w * 64 + n * 16 + l15;
        vb[n] = *(const bf16x8*)(kvs + row * 64 + ((chunk ^ (row & 7)) << 3));
      }
#pragma unroll
      for (int m = 0; m < 4; ++m)
#pragma unroll
        for (int n = 0; n < 4; ++n)
          acc[m][n] = __builtin_amdgcn_mfma_f32_16x16x32_bf16(pa[m], vb[n], acc[m][n], 0, 0, 0);
    }
  }

  // epilogue: divide by lrun, store Ot[l][c] bf16
#pragma unroll
  for (int m = 0; m < 4; ++m) {
    f32x4 lr = *(const f32x4*)(&lrun[m * 16 + lhi * 4]);
    f32x4 inv;
#pragma unroll
    for (int r = 0; r < 4; ++r) inv[r] = 1.0f / lr[r];
#pragma unroll
    for (int n = 0; n < 4; ++n) {
      int c = w * 64 + n * 16 + l15;
#pragma unroll
      for (int r = 0; r < 4; ++r) {
        int l = q0 + m * 16 + lhi * 4 + r;
        ot[(size_t)(b * L_ + l) * C_ + c] = f2bf(acc[m][n][r] * inv[r]);
      }
    }
  }
}

extern "C" void kernel_launch(void* const* d_in, const int* in_sizes, int n_in,
                              void* d_out, int out_size, void* d_ws, size_t ws_size,
                              hipStream_t stream) {
  const float* x  = (const float*)d_in[0];
  const float* nw = (const float*)d_in[1];
  const float* nb = (const float*)d_in[2];
  const float* qw = (const float*)d_in[3];
  const float* qb = (const float*)d_in[4];
  const float* ow = (const float*)d_in[5];
  const float* ob = (const float*)d_in[6];
  float* out = (float*)d_out;
  char* ws = (char*)d_ws;

  // workspace layout (bytes), total ~194 MB
  float*    mu   = (float*)(ws + 0);
  float*    rs   = (float*)(ws + 1024);
  uint16_t* wq   = (uint16_t*)(ws + 4096);                       // 1536*512
  uint16_t* wo   = (uint16_t*)(ws + 4096 + 1572864);             // 512*512
  uint16_t* xnT  = (uint16_t*)(ws + 2101248);                    // 8*4096*512
  uint16_t* qkvT = (uint16_t*)(ws + 35655680);                   // 8*4096*1536
  uint16_t* vn   = (uint16_t*)(ws + 136318976);                  // 8*512*4096
  uint16_t* otb  = (uint16_t*)(ws + 169873408);                  // 8*4096*512

  k_cvt_bf16<<<dim3((1536 * 512) / 1024), 256, 0, stream>>>(qw, wq, 1536 * 512);
  k_cvt_bf16<<<dim3((512 * 512) / 1024), 256, 0, stream>>>(ow, wo, 512 * 512);
  k_gnstats<<<dim3(256), 256, 0, stream>>>(x, mu, rs);
  k_normT<<<dim3(64, 8, 8), 256, 0, stream>>>(x, nw, nb, mu, rs, xnT);
  k_gemm<0><<<dim3(12, 32, 8), 256, 0, stream>>>(xnT, 512, (long long)4096 * 512,
                                                 wq, 512, 0LL,
                                                 qkvT, (long long)4096 * 1536, qb, nullptr);
  k_vT<<<dim3(64, 8, 8), 256, 0, stream>>>(qkvT, vn);
  k_attn<<<dim3(64, 8), 512, 0, stream>>>(qkvT, vn, otb);
  k_gemm<1><<<dim3(32, 4, 8), 256, 0, stream>>>(wo, 512, 0LL,
                                                otb, 512, (long long)4096 * 512,
                                                out, (long long)512 * 4096, ob, x);
}

// Round 2
// 661.817 us; speedup vs baseline: 1.1423x; 1.1423x over previous
//
#include <hip/hip_runtime.h>
#include <cstdint>

// Problem constants
static constexpr int B_ = 8, C_ = 512, L_ = 4096, NG_ = 32;
static constexpr float RSCALE = 0.04419417382415922f; // 1/sqrt(512)

using f32x4  = __attribute__((ext_vector_type(4))) float;
using bf16x8 = __attribute__((ext_vector_type(8))) short;

__device__ __forceinline__ uint16_t f2bf(float f) {
  union { float f; uint32_t u; } v{f};
  uint32_t r = (v.u + 0x7fffu + ((v.u >> 16) & 1u)) >> 16;
  return (uint16_t)r;
}

// ---------------- K0: f32 -> bf16 convert (weights) ----------------
__global__ __launch_bounds__(256) void k_cvt_bf16(const float* __restrict__ in,
                                                  uint16_t* __restrict__ out, int n) {
  int i = (blockIdx.x * 256 + threadIdx.x) * 4;
  if (i + 3 < n) {
    float4 v = *(const float4*)(in + i);
    union { uint16_t s[4]; uint2 u; } o;
    o.s[0] = f2bf(v.x); o.s[1] = f2bf(v.y); o.s[2] = f2bf(v.z); o.s[3] = f2bf(v.w);
    *(uint2*)(out + i) = o.u;
  }
}

// ---------------- K1: GroupNorm stats ----------------
__global__ __launch_bounds__(256) void k_gnstats(const float* __restrict__ x,
                                                 float* __restrict__ mu, float* __restrict__ rs) {
  int bg = blockIdx.x;
  const float* p = x + (size_t)bg * (16 * L_);
  float s = 0.f, s2 = 0.f;
#pragma unroll 8
  for (int i = 0; i < 64; ++i) {
    float4 v = *(const float4*)(p + (threadIdx.x + i * 256) * 4);
    s  += v.x + v.y + v.z + v.w;
    s2 += v.x * v.x + v.y * v.y + v.z * v.z + v.w * v.w;
  }
  for (int o = 32; o; o >>= 1) { s += __shfl_down(s, o); s2 += __shfl_down(s2, o); }
  __shared__ float as_[4], as2_[4];
  int w = threadIdx.x >> 6;
  if ((threadIdx.x & 63) == 0) { as_[w] = s; as2_[w] = s2; }
  __syncthreads();
  if (threadIdx.x == 0) {
    float S = as_[0] + as_[1] + as_[2] + as_[3];
    float S2 = as2_[0] + as2_[1] + as2_[2] + as2_[3];
    float m = S / 65536.0f;
    float var = S2 / 65536.0f - m * m;
    mu[bg] = m; rs[bg] = rsqrtf(var + 1e-5f);
  }
}

// ---------------- K2: normalize + transpose: x[b][c][l] f32 -> xnT[b][l][c] bf16 ----------------
__global__ __launch_bounds__(256) void k_normT(const float* __restrict__ x,
                                               const float* __restrict__ nw, const float* __restrict__ nb,
                                               const float* __restrict__ mu, const float* __restrict__ rs,
                                               uint16_t* __restrict__ xnT) {
  __shared__ __align__(16) uint16_t t[64][72];
  int l0 = blockIdx.x * 64, c0 = blockIdx.y * 64, b = blockIdx.z;
#pragma unroll
  for (int i = 0; i < 4; ++i) {
    int idx = threadIdx.x + i * 256;
    int row = idx >> 4, q = idx & 15;
    int c = c0 + row;
    float m_ = mu[b * NG_ + (c >> 4)], r_ = rs[b * NG_ + (c >> 4)];
    float sc = r_ * nw[c], sh = nb[c] - m_ * sc;
    float4 v = *(const float4*)(x + (size_t)(b * C_ + c) * L_ + l0 + q * 4);
    int lb = q * 4;
    t[lb + 0][row] = f2bf(v.x * sc + sh);
    t[lb + 1][row] = f2bf(v.y * sc + sh);
    t[lb + 2][row] = f2bf(v.z * sc + sh);
    t[lb + 3][row] = f2bf(v.w * sc + sh);
  }
  __syncthreads();
#pragma unroll
  for (int i = 0; i < 2; ++i) {
    int idx = threadIdx.x + i * 256;
    int row = idx >> 3, ch = idx & 7;
    uint4 v = *(const uint4*)(&t[row][ch * 8]);
    *(uint4*)(xnT + (size_t)(b * L_ + l0 + row) * C_ + c0 + ch * 8) = v;
  }
}

// ---------------- K4: V transpose: qkvT[b][l][1024+c] -> vn[b][c][l] ----------------
__global__ __launch_bounds__(256) void k_vT(const uint16_t* __restrict__ qkvT, uint16_t* __restrict__ vn) {
  __shared__ __align__(16) uint16_t t[64][72];
  int l0 = blockIdx.x * 64, c0 = blockIdx.y * 64, b = blockIdx.z;
#pragma unroll
  for (int i = 0; i < 2; ++i) {
    int idx = threadIdx.x + i * 256;
    int row = idx >> 3, ch = idx & 7;
    uint16_t v[8];
    *(uint4*)v = *(const uint4*)(qkvT + (size_t)(b * L_ + l0 + row) * 1536 + 1024 + c0 + ch * 8);
#pragma unroll
    for (int j = 0; j < 8; ++j) t[ch * 8 + j][row] = v[j];
  }
  __syncthreads();
#pragma unroll
  for (int i = 0; i < 2; ++i) {
    int idx = threadIdx.x + i * 256;
    int row = idx >> 3, ch = idx & 7;
    *(uint4*)(vn + (size_t)(b * C_ + c0 + row) * L_ + l0 + ch * 8) = *(const uint4*)(&t[row][ch * 8]);
  }
}

// ---------------- GEMM (128x128 tile, BK=64, 4 waves, swizzled LDS) ----------------
template <int MODE>
__global__ __launch_bounds__(256, 2) void k_gemm(const uint16_t* __restrict__ Ag, int lda, long long strideA,
                                                 const uint16_t* __restrict__ Bg, int ldb, long long strideB,
                                                 void* __restrict__ Cg, long long strideC,
                                                 const float* __restrict__ bias,
                                                 const float* __restrict__ resid) {
  __shared__ __align__(16) uint16_t Asm[128 * 64], Bsm[128 * 64];
  int b = blockIdx.z;
  int m0 = blockIdx.y * 128, n0 = blockIdx.x * 128;
  const uint16_t* A = Ag + (size_t)b * strideA;
  const uint16_t* Bp = Bg + (size_t)b * strideB;
  int lane = threadIdx.x & 63, w = threadIdx.x >> 6;
  int wm = w >> 1, wn = w & 1;
  int l15 = lane & 15, lhi = lane >> 4;
  f32x4 acc[4][4] = {};
  for (int kt = 0; kt < 512; kt += 64) {
#pragma unroll
    for (int i = 0; i < 4; ++i) {
      int idx = threadIdx.x + i * 256;
      int row = idx >> 3, cs = idx & 7, cg = cs ^ (row & 7);
      *(uint4*)(Asm + row * 64 + cs * 8) = *(const uint4*)(A + (size_t)(m0 + row) * lda + kt + cg * 8);
      *(uint4*)(Bsm + row * 64 + cs * 8) = *(const uint4*)(Bp + (size_t)(n0 + row) * ldb + kt + cg * 8);
    }
    __syncthreads();
#pragma unroll
    for (int kk = 0; kk < 2; ++kk) {
      bf16x8 af[4], bfr[4];
      int chunk = kk * 4 + lhi;
#pragma unroll
      for (int m = 0; m < 4; ++m) {
        int row = wm * 64 + m * 16 + l15;
        af[m] = *(const bf16x8*)(Asm + row * 64 + ((chunk ^ (row & 7)) << 3));
      }
#pragma unroll
      for (int n = 0; n < 4; ++n) {
        int row = wn * 64 + n * 16 + l15;
        bfr[n] = *(const bf16x8*)(Bsm + row * 64 + ((chunk ^ (row & 7)) << 3));
      }
#pragma unroll
      for (int m = 0; m < 4; ++m)
#pragma unroll
        for (int n = 0; n < 4; ++n)
          acc[m][n] = __builtin_amdgcn_mfma_f32_16x16x32_bf16(af[m], bfr[n], acc[m][n], 0, 0, 0);
    }
    __syncthreads();
  }
  if (MODE == 0) {
    uint16_t* Cp = (uint16_t*)Cg + (size_t)b * strideC;
#pragma unroll
    for (int n = 0; n < 4; ++n) {
      int col = n0 + wn * 64 + n * 16 + l15;
      float bs = bias[col];
      float scl = (col < 512) ? RSCALE : 1.0f;
#pragma unroll
      for (int m = 0; m < 4; ++m) {
        int rowb = m0 + wm * 64 + m * 16 + lhi * 4;
#pragma unroll
        for (int r = 0; r < 4; ++r)
          Cp[(size_t)(rowb + r) * 1536 + col] = f2bf((acc[m][n][r] + bs) * scl);
      }
    }
  } else {
    float* Cp = (float*)Cg + (size_t)b * strideC;
    const float* Xp = resid + (size_t)b * strideC;
#pragma unroll
    for (int m = 0; m < 4; ++m) {
      int rowb = m0 + wm * 64 + m * 16 + lhi * 4;
#pragma unroll
      for (int n = 0; n < 4; ++n) {
        int col = n0 + wn * 64 + n * 16 + l15;
#pragma unroll
        for (int r = 0; r < 4; ++r) {
          float v = acc[m][n][r] + bias[rowb + r] + Xp[(size_t)(rowb + r) * 4096 + col];
          Cp[(size_t)(rowb + r) * 4096 + col] = v;
        }
      }
    }
  }
}

// ---------------- K5: flash attention v2 ----------------
// Q in registers (per-wave l-frag), K double-buffered in LDS, V direct global->regs,
// softmax state in registers, 2 barriers per iteration.
__global__ __launch_bounds__(512, 2) void k_attn(const uint16_t* __restrict__ qkvT,
                                                 const uint16_t* __restrict__ vn,
                                                 uint16_t* __restrict__ ot) {
  __shared__ __align__(16) uint16_t kbuf[2][64 * 512]; // 128 KB, double-buffered K tile [s][c]
  __shared__ __align__(16) uint16_t ps[64 * 64];       // 8 KB, P tile [l][s]
  __shared__ __align__(16) float redm[2][4][16], reds[2][4][16];
  __shared__ __align__(16) float alph[64];

  const int tid = threadIdx.x, lane = tid & 63, w = tid >> 6;
  const int l15 = lane & 15, lhi = lane >> 4;
  const int b = blockIdx.y, q0 = blockIdx.x * 64;
  const int nf = w & 3, mh = w >> 2; // nf: l-frag (16 l), mh: s-half (32 s)

  const uint16_t* qg = qkvT + (size_t)(b * L_ + q0) * 1536;
  const uint16_t* kg = qkvT + (size_t)b * L_ * 1536 + 512;
  const uint16_t* vg = vn + (size_t)b * C_ * L_ + (size_t)(w * 64) * L_; // wave's c-slice

  // ---- Q into registers: qr[kc] = Q[l = nf*16+l15][kc*32 + lhi*8 .. +8]
  bf16x8 qr[16];
  {
    const uint16_t* qrow = qg + (size_t)(nf * 16 + l15) * 1536 + lhi * 8;
#pragma unroll
    for (int kc = 0; kc < 16; ++kc) qr[kc] = *(const bf16x8*)(qrow + kc * 32);
  }

  float mrun = -1e30f, lrun = 0.0f;
  f32x4 acc[4][4] = {};

  // ---- prologue: stage K tile 0 into kbuf[0] (linear global read, swizzled LDS write)
#pragma unroll
  for (int i = 0; i < 8; ++i) {
    int row = w * 8 + i;
    bf16x8 t = *(const bf16x8*)(kg + (size_t)row * 1536 + lane * 8);
    *(bf16x8*)(kbuf[0] + row * 512 + ((lane ^ (row & 7)) << 3)) = t;
  }
  __syncthreads();

  for (int st = 0; st < 64; ++st) {
    const uint16_t* kcur = kbuf[st & 1];
    uint16_t* knxt = kbuf[(st + 1) & 1];
    const int stn = (st + 1) & 63; // wraps to 0 on last iter (harmless)

    // issue next K tile global loads early (hidden under QK)
    bf16x8 ktmp[8];
#pragma unroll
    for (int i = 0; i < 8; ++i) {
      int row = w * 8 + i;
      ktmp[i] = *(const bf16x8*)(kg + (size_t)(stn * 64 + row) * 1536 + lane * 8);
    }

    // ---- QK^T: S^T[s][l], A = K (LDS), B = Q (regs)
    f32x4 sfr[2] = {};
#pragma unroll
    for (int kc = 0; kc < 16; ++kc) {
      int chunk = kc * 4 + lhi;
#pragma unroll
      for (int i = 0; i < 2; ++i) {
        int srow = (mh * 2 + i) * 16 + l15;
        bf16x8 ak = *(const bf16x8*)(kcur + srow * 512 + ((chunk ^ (srow & 7)) << 3));
        sfr[i] = __builtin_amdgcn_mfma_f32_16x16x32_bf16(ak, qr[kc], sfr[i], 0, 0, 0);
      }
    }

    // partial column-max over this wave's 32 s-rows
    float pm = fmaxf(fmaxf(fmaxf(sfr[0][0], sfr[0][1]), fmaxf(sfr[0][2], sfr[0][3])),
                     fmaxf(fmaxf(sfr[1][0], sfr[1][1]), fmaxf(sfr[1][2], sfr[1][3])));
    pm = fmaxf(pm, __shfl_xor(pm, 16));
    pm = fmaxf(pm, __shfl_xor(pm, 32));
    if (lhi == 0) redm[mh][nf][l15] = pm;

    // write staged K to other buffer (covered by B1's drain)
#pragma unroll
    for (int i = 0; i < 8; ++i) {
      int row = w * 8 + i;
      *(bf16x8*)(knxt + row * 512 + ((lane ^ (row & 7)) << 3)) = ktmp[i];
    }

    __syncthreads(); // B1: redm visible, knxt staged

    // ---- softmax (state in regs, duplicated across lhi / mh)
    float m_old = mrun;
    float tm = fmaxf(redm[0][nf][l15], redm[1][nf][l15]);
    float m_new = fmaxf(m_old, tm);
    float alpha = __expf(m_old - m_new);
    if (w < 4 && lhi == 0) alph[nf * 16 + l15] = alpha;

    float p[2][4], psum = 0.f;
#pragma unroll
    for (int i = 0; i < 2; ++i)
#pragma unroll
      for (int r = 0; r < 4; ++r) { p[i][r] = __expf(sfr[i][r] - m_new); psum += p[i][r]; }
    psum += __shfl_xor(psum, 16);
    psum += __shfl_xor(psum, 32);
    if (lhi == 0) reds[mh][nf][l15] = psum;

    // P -> ps (bf16, swizzled): l = nf*16+l15, s = mh*32 + i*16 + lhi*4 + r
    {
      int l = nf * 16 + l15;
#pragma unroll
      for (int i = 0; i < 2; ++i) {
        int s0 = (mh * 2 + i) * 16 + lhi * 4;
        union { uint16_t h[4]; uint2 u; } pk;
#pragma unroll
        for (int r = 0; r < 4; ++r) pk.h[r] = f2bf(p[i][r]);
        int chunk = s0 >> 3, off = s0 & 7;
        *(uint2*)(ps + l * 64 + ((chunk ^ (l & 7)) << 3) + off) = pk.u;
      }
    }

    // issue V fragment loads (direct to regs; wave-private c-slice, no reuse -> no LDS)
    bf16x8 vb[2][4];
#pragma unroll
    for (int kk = 0; kk < 2; ++kk)
#pragma unroll
      for (int n = 0; n < 4; ++n)
        vb[kk][n] = *(const bf16x8*)(vg + (size_t)(n * 16 + l15) * L_ + st * 64 + kk * 32 + lhi * 8);

    mrun = m_new;

    __syncthreads(); // B2: ps, reds, alph visible

    lrun = lrun * alpha + (reds[0][nf][l15] + reds[1][nf][l15]);

    // rescale acc by alph[l], l = m*16 + lhi*4 + r
#pragma unroll
    for (int m = 0; m < 4; ++m) {
      f32x4 a4 = *(const f32x4*)(&alph[m * 16 + lhi * 4]);
#pragma unroll
      for (int n = 0; n < 4; ++n)
#pragma unroll
        for (int r = 0; r < 4; ++r) acc[m][n][r] *= a4[r];
    }

    // ---- PV: Ot[l][c] += P[l][s] (LDS) * V[c][s] (regs)
#pragma unroll
    for (int kk = 0; kk < 2; ++kk) {
      int chunk = kk * 4 + lhi;
      bf16x8 pa[4];
#pragma unroll
      for (int m = 0; m < 4; ++m) {
        int row = m * 16 + l15;
        pa[m] = *(const bf16x8*)(ps + row * 64 + ((chunk ^ (row & 7)) << 3));
      }
#pragma unroll
      for (int m = 0; m < 4; ++m)
#pragma unroll
        for (int n = 0; n < 4; ++n)
          acc[m][n] = __builtin_amdgcn_mfma_f32_16x16x32_bf16(pa[m], vb[kk][n], acc[m][n], 0, 0, 0);
    }
  }

  // ---- epilogue: share lrun across waves (reuse alph), divide, store
  __syncthreads();
  if (w < 4 && lhi == 0) alph[nf * 16 + l15] = lrun;
  __syncthreads();
#pragma unroll
  for (int m = 0; m < 4; ++m) {
    f32x4 lr = *(const f32x4*)(&alph[m * 16 + lhi * 4]);
    f32x4 inv;
#pragma unroll
    for (int r = 0; r < 4; ++r) inv[r] = 1.0f / lr[r];
#pragma unroll
    for (int n = 0; n < 4; ++n) {
      int c = w * 64 + n * 16 + l15;
#pragma unroll
      for (int r = 0; r < 4; ++r) {
        int l = q0 + m * 16 + lhi * 4 + r;
        ot[(size_t)(b * L_ + l) * C_ + c] = f2bf(acc[m][n][r] * inv[r]);
      }
    }
  }
}

extern "C" void kernel_launch(void* const* d_in, const int* in_sizes, int n_in,
                              void* d_out, int out_size, void* d_ws, size_t ws_size,
                              hipStream_t stream) {
  const float* x  = (const float*)d_in[0];
  const float* nw = (const float*)d_in[1];
  const float* nb = (const float*)d_in[2];
  const float* qw = (const float*)d_in[3];
  const float* qb = (const float*)d_in[4];
  const float* ow = (const float*)d_in[5];
  const float* ob = (const float*)d_in[6];
  float* out = (float*)d_out;
  char* ws = (char*)d_ws;

  float*    mu   = (float*)(ws + 0);
  float*    rs   = (float*)(ws + 1024);
  uint16_t* wq   = (uint16_t*)(ws + 4096);                       // 1536*512
  uint16_t* wo   = (uint16_t*)(ws + 4096 + 1572864);             // 512*512
  uint16_t* xnT  = (uint16_t*)(ws + 2101248);                    // 8*4096*512
  uint16_t* qkvT = (uint16_t*)(ws + 35655680);                   // 8*4096*1536
  uint16_t* vn   = (uint16_t*)(ws + 136318976);                  // 8*512*4096
  uint16_t* otb  = (uint16_t*)(ws + 169873408);                  // 8*4096*512

  k_cvt_bf16<<<dim3((1536 * 512) / 1024), 256, 0, stream>>>(qw, wq, 1536 * 512);
  k_cvt_bf16<<<dim3((512 * 512) / 1024), 256, 0, stream>>>(ow, wo, 512 * 512);
  k_gnstats<<<dim3(256), 256, 0, stream>>>(x, mu, rs);
  k_normT<<<dim3(64, 8, 8), 256, 0, stream>>>(x, nw, nb, mu, rs, xnT);
  k_gemm<0><<<dim3(12, 32, 8), 256, 0, stream>>>(xnT, 512, (long long)4096 * 512,
                                                 wq, 512, 0LL,
                                                 qkvT, (long long)4096 * 1536, qb, nullptr);
  k_vT<<<dim3(64, 8, 8), 256, 0, stream>>>(qkvT, vn);
  k_attn<<<dim3(64, 8), 512, 0, stream>>>(qkvT, vn, otb);
  k_gemm<1><<<dim3(32, 4, 8), 256, 0, stream>>>(wo, 512, 0LL,
                                                otb, 512, (long long)4096 * 512,
                                                out, (long long)512 * 4096, ob, x);
}